// Round 9
// baseline (367.499 us; speedup 1.0000x reference)
//
#include <hip/hip_runtime.h>
#include <math.h>

#define B 128
#define T 1024
#define H 256
#define L 16
#define INV_TEMP (1.0f/0.07f)
#define NEG_INF -1e30f

// ws layout (only seg<nseg regions are ever written/read -> no memset):
//   ws_pp   : float[B][4][L][H]   per-seg prototype partial sums   8 MB
//   ws_cntp : int[B][4][L]        per-seg label counts             32 KB
//   ws_dots : float[2][B][T][L]   partial dots per H-half          16 MB

// ---------------------------------------------------------------------------
// Kernel 1: prototype partial sums. grid = B * 2 chunks * 4 segs = 1024
// blocks. Block owns a disjoint [b][seg][L][chunk*128..+128) slice -> plain
// stores, no cross-block atomics. Wave-private slabs. Accumulate with LDS
// atomicAdd (ds_add_f32, NO return value): unlike the R4-R8 read-modify-write
// this creates no lgkmcnt dependency chain when consecutive tokens share a
// label -- the LDS pipe serializes same-address adds internally, the wave
// never waits. Block 0 zeroes out[0] (replaces memset dispatch).
__global__ __launch_bounds__(256) void proto_kernel(
    const float* __restrict__ feat, const int* __restrict__ dlen,
    const int* __restrict__ labels, float* __restrict__ ws_pp,
    int* __restrict__ ws_cntp, float* __restrict__ out) {
  __shared__ float acc[4][L * 128];   // 32 KB, wave-private slabs
  __shared__ int labs[256];
  __shared__ int cnt[L];

  const int bx = blockIdx.x;
  const int b = bx >> 3;
  const int chunk = (bx >> 2) & 1;
  const int seg = bx & 3;
  const int tid = threadIdx.x;
  const int w = tid >> 6;
  const int lane = tid & 63;

  if (bx == 0 && tid == 0) out[0] = 0.f;

  const int len = dlen[b];
  if (seg * 256 >= len) return;   // invalid segment: consumers skip seg>=nseg

  for (int i = tid; i < 4 * L * 128; i += 256) ((float*)acc)[i] = 0.f;
  labs[tid] = labels[(size_t)b * T + seg * 256 + tid];
  if (tid < L) cnt[tid] = 0;
  __syncthreads();

  if (chunk == 0 && (seg * 256 + tid) < len) atomicAdd(&cnt[labs[tid]], 1);

  int nt = len - seg * 256 - w * 64;   // tokens this wave processes
  if (nt > 64) nt = 64;
  const float2* fbase = (const float2*)(feat +
      ((size_t)b * T + seg * 256 + w * 64) * H + chunk * 128);
  float* a = acc[w];

  int j = 0;
  for (; j + 4 <= nt; j += 4) {
    float2 f0 = fbase[(size_t)(j + 0) * (H / 2) + lane];
    float2 f1 = fbase[(size_t)(j + 1) * (H / 2) + lane];
    float2 f2 = fbase[(size_t)(j + 2) * (H / 2) + lane];
    float2 f3 = fbase[(size_t)(j + 3) * (H / 2) + lane];
    const int l0 = labs[w * 64 + j + 0];
    const int l1 = labs[w * 64 + j + 1];
    const int l2 = labs[w * 64 + j + 2];
    const int l3 = labs[w * 64 + j + 3];
    float* p0 = &a[l0 * 128 + lane * 2];
    atomicAdd(p0, f0.x); atomicAdd(p0 + 1, f0.y);
    float* p1 = &a[l1 * 128 + lane * 2];
    atomicAdd(p1, f1.x); atomicAdd(p1 + 1, f1.y);
    float* p2 = &a[l2 * 128 + lane * 2];
    atomicAdd(p2, f2.x); atomicAdd(p2 + 1, f2.y);
    float* p3 = &a[l3 * 128 + lane * 2];
    atomicAdd(p3, f3.x); atomicAdd(p3 + 1, f3.y);
  }
  for (; j < nt; ++j) {
    float2 f = fbase[(size_t)j * (H / 2) + lane];
    const int lab = labs[w * 64 + j];
    float* p = &a[lab * 128 + lane * 2];
    atomicAdd(p, f.x); atomicAdd(p + 1, f.y);
  }
  __syncthreads();

  float* op = ws_pp + (((size_t)b * 4 + seg) * L) * H + chunk * 128;
  for (int e = tid; e < L * 128; e += 256) {
    const float s = acc[0][e] + acc[1][e] + acc[2][e] + acc[3][e];
    op[(e >> 7) * H + (e & 127)] = s;
  }
  if (chunk == 0 && tid < L) ws_cntp[(b * 4 + seg) * L + tid] = cnt[tid];
}

// ---------------------------------------------------------------------------
// Kernel 2 (R4/R8-proven, unchanged): partial dots. grid = B * 2 H-halves =
// 256 blocks, 4 tokens/thread -> 16 fma per uniform ds_read_b128. No forced
// cb unroll (regressed in R5/R7).
__global__ __launch_bounds__(256) void dots_kernel(
    const float* __restrict__ feat, const int* __restrict__ dlen,
    const float* __restrict__ ws_pp, const int* __restrict__ ws_cntp,
    float* __restrict__ ws_dots) {
  __shared__ float pr[L * 128];
  __shared__ int cnts[L];

  const int bx = blockIdx.x;
  const int b = bx >> 1;
  const int half = bx & 1;
  const int tid = threadIdx.x;

  const int len = dlen[b];
  const int nseg = (len + 255) >> 8;   // 1..4 valid segments

  if (tid < L) {
    const int* cp = ws_cntp + b * 4 * L + tid;
    int c = 0;
    for (int s = 0; s < nseg; ++s) c += cp[s * L];
    cnts[tid] = c;
  }
  __syncthreads();

  const float* gp = ws_pp + ((size_t)b * 4 * L) * H + half * 128;
  for (int i = tid; i < L * 128; i += 256) {
    const int l = i >> 7, c = i & 127;
    float s = 0.f;
    for (int sg = 0; sg < nseg; ++sg) s += gp[(sg * L + l) * H + c];
    const int cn = cnts[l];
    pr[i] = s * (cn > 0 ? 1.f / (float)cn : 0.f);
  }
  __syncthreads();

  const float4* fv[4];
#pragma unroll
  for (int k = 0; k < 4; ++k) {
    const int t = k * 256 + tid;
    fv[k] = (const float4*)(feat + ((size_t)b * T + t) * H + half * 128);
  }

  float dot[4][L];
#pragma unroll
  for (int k = 0; k < 4; ++k)
#pragma unroll
    for (int l = 0; l < L; ++l) dot[k][l] = 0.f;

  for (int cb = 0; cb < 8; ++cb) {   // 4 quads (64B) per burst per token
    float4 f[4][4];
#pragma unroll
    for (int k = 0; k < 4; ++k) {
      if (k < nseg) {                // block-uniform: skip dead token groups
#pragma unroll
        for (int q = 0; q < 4; ++q) f[k][q] = fv[k][cb * 4 + q];
      }
    }
#pragma unroll
    for (int q = 0; q < 4; ++q) {
#pragma unroll
      for (int l = 0; l < L; ++l) {
        const float4 p = *(const float4*)&pr[l * 128 + cb * 16 + q * 4];
#pragma unroll
        for (int k = 0; k < 4; ++k) {
          if (k < nseg) {
            dot[k][l] += f[k][q].x * p.x + f[k][q].y * p.y +
                         f[k][q].z * p.z + f[k][q].w * p.w;
          }
        }
      }
    }
  }

#pragma unroll
  for (int k = 0; k < 4; ++k) {
    const int t = k * 256 + tid;
    if (k < nseg && t < len) {
      float4* d = (float4*)(ws_dots + (((size_t)half * B + b) * T + t) * L);
#pragma unroll
      for (int q = 0; q < 4; ++q)
        d[q] = make_float4(dot[k][q * 4], dot[k][q * 4 + 1],
                           dot[k][q * 4 + 2], dot[k][q * 4 + 3]);
    }
  }
}

// ---------------------------------------------------------------------------
// Kernel 3 (unchanged): combine halves, log-softmax, masked mean. grid = B*4.
__global__ __launch_bounds__(256) void loss_kernel(
    const int* __restrict__ dlen, const int* __restrict__ labels,
    const int* __restrict__ ws_cntp, const float* __restrict__ ws_dots,
    float* __restrict__ out) {
  __shared__ int cnts[L];
  __shared__ float red[256];

  const int b = blockIdx.x >> 2;
  const int seg = blockIdx.x & 3;
  const int tid = threadIdx.x;

  const int len = dlen[b];
  if (seg * 256 >= len) return;        // contributes exactly 0
  const int nseg = (len + 255) >> 8;

  if (tid < L) {
    const int* cp = ws_cntp + b * 4 * L + tid;
    int c = 0;
    for (int s = 0; s < nseg; ++s) c += cp[s * L];
    cnts[tid] = c;
  }
  __syncthreads();

  const int t = seg * 256 + tid;
  float tok = 0.f;

  if (t < len) {
    const float* d0 = ws_dots + ((size_t)b * T + t) * L;
    const float* d1 = d0 + (size_t)B * T * L;
    float lg[L];
#pragma unroll
    for (int l = 0; l < L; ++l) {
      const float d = d0[l] + d1[l];
      lg[l] = (cnts[l] > 0) ? d * INV_TEMP : NEG_INF;
    }
    float m = lg[0];
#pragma unroll
    for (int l = 1; l < L; ++l) m = fmaxf(m, lg[l]);
    float se = 0.f;
#pragma unroll
    for (int l = 0; l < L; ++l) se += expf(lg[l] - m);
    const float lsp = m + logf(se);

    const int lab = labels[(size_t)b * T + t];
    float pos = 0.f;
#pragma unroll
    for (int l = 0; l < L; ++l) pos += (l == lab) ? lg[l] : 0.f;

    tok = lsp - pos;
  }

  red[tid] = tok;
  __syncthreads();
#pragma unroll
  for (int s = 128; s > 0; s >>= 1) {
    if (tid < s) red[tid] += red[tid + s];
    __syncthreads();
  }
  if (tid == 0) atomicAdd(out, red[0] / ((float)len * (float)B));
}

extern "C" void kernel_launch(void* const* d_in, const int* in_sizes, int n_in,
                              void* d_out, int out_size, void* d_ws, size_t ws_size,
                              hipStream_t stream) {
  const float* feat = (const float*)d_in[0];
  const int* dlen = (const int*)d_in[1];
  const int* labels = (const int*)d_in[2];
  float* out = (float*)d_out;

  float* ws_pp = (float*)d_ws;                           // B*4*L*H floats
  int* ws_cntp = (int*)(ws_pp + (size_t)B * 4 * L * H);  // B*4*L ints
  float* ws_dots = (float*)(ws_cntp + (size_t)B * 4 * L);// 2*B*T*L floats

  proto_kernel<<<B * 8, 256, 0, stream>>>(feat, dlen, labels, ws_pp, ws_cntp, out);
  dots_kernel<<<B * 2, 256, 0, stream>>>(feat, dlen, ws_pp, ws_cntp, ws_dots);
  loss_kernel<<<B * 4, 256, 0, stream>>>(dlen, labels, ws_cntp, ws_dots, out);
}